// Round 3
// baseline (215.219 us; speedup 1.0000x reference)
//
#include <hip/hip_runtime.h>
#include <hip/hip_bf16.h>

#define N_EMBD 1024
#define NW     110592
#define NCHUNK 96

typedef __attribute__((ext_vector_type(8)))  short          short8;
typedef __attribute__((ext_vector_type(8)))  unsigned short ushort8;
typedef __attribute__((ext_vector_type(16))) float          floatx16;
typedef __attribute__((ext_vector_type(4)))  float          float4v;

// chunk sizes: 48 x 1024, 24 x 2048, 24 x 512
__device__ __forceinline__ void chunk_info(int l, int& S, int& off) {
  if (l < 48)      { S = 1024; off = l * 1024; }
  else if (l < 72) { S = 2048; off = 49152 + (l - 48) * 2048; }
  else             { S = 512;  off = 98304 + (l - 72) * 512; }
}

// fp32 -> bf16 round-to-nearest-even
__device__ __forceinline__ unsigned short f2bf(float f) {
  unsigned u = __float_as_uint(f);
  u += 0x7fffu + ((u >> 16) & 1u);
  return (unsigned short)(u >> 16);
}
__device__ __forceinline__ float bf2f(unsigned short u) {
  return __uint_as_float(((unsigned)u) << 16);
}

// ---------------- transpose: xswz[kb][b][e] = bf16(P[b][kb*8+e])
__global__ __launch_bounds__(256) void xpose_kernel(
    const float* __restrict__ P, unsigned short* __restrict__ xswz) {
  int t = blockIdx.x * 256 + threadIdx.x;   // t < (NW/8)*32
  int b = t & 31, kb = t >> 5;
  const float* src = P + (size_t)b * NW + (size_t)kb * 8;
  float4v v0 = *(const float4v*)(src);
  float4v v1 = *(const float4v*)(src + 4);
  ushort8 o;
#pragma unroll
  for (int j = 0; j < 4; ++j) { o[j] = f2bf(v0[j]); o[j + 4] = f2bf(v1[j]); }
  *(ushort8*)(xswz + (size_t)t * 8) = o;
}

// ---------------- encoder: barrier-free, wave-private reg-staged GEMM
// flat grid 768 tiles, heavy chunks first. wave tile 32(batch) x 32(cols), K-step 32, prefetch depth 2.
__global__ __launch_bounds__(256) void enc_kernel(
    const unsigned short* __restrict__ xswz, const float* __restrict__ We,
    unsigned short* __restrict__ reps) {
  __shared__ float ldsW[4][2][32 * 36];
  int id = blockIdx.x;
  int l, ti;
  if (id < 192)      { l = 48 + (id >> 3); ti = id & 7; }
  else if (id < 576) { int j = id - 192; l = j >> 3; ti = j & 7; }
  else               { int j = id - 576; l = 72 + (j >> 3); ti = j & 7; }
  int S, off; chunk_info(l, S, off);

  int tid = threadIdx.x, w = tid >> 6, lane = tid & 63;
  int lo = lane & 31, hi = lane >> 5;
  int r8 = lane >> 3, c4 = (lane & 7) << 2;
  int cw = ti * 128 + w * 32;

  const float* gW = We + (size_t)l * (2048 * N_EMBD) + (size_t)r8 * N_EMBD + cw + c4;
  const unsigned short* Ab = xswz + (size_t)off * 32 + lo * 8;
  float* L0 = &ldsW[w][0][0];
  float* L1 = &ldsW[w][1][0];
  int nt = S >> 5;
  int kAmax = S - 8;
  int kWmax = (nt - 1) << 5;

#define LW(dst, k0) { int kk_ = (k0); _Pragma("unroll") \
    for (int q = 0; q < 4; ++q) dst[q] = *(const float4v*)(gW + (size_t)(kk_ + 8 * q) * N_EMBD); }
#define AF(ka) (*(const short8*)(Ab + (size_t)((ka) < kAmax ? (ka) : kAmax) * 32))
#define STW(L, src) { _Pragma("unroll") \
    for (int q = 0; q < 4; ++q) *(float4v*)((L) + (r8 + 8 * q) * 36 + c4) = src[q]; }
#define BRD(L, ks, dst) { _Pragma("unroll") \
    for (int j = 0; j < 8; ++j) dst[j] = (short)f2bf((L)[((ks) * 16 + hi * 8 + j) * 36 + lo]); }

  float4v wa[4], wb[4];
  LW(wa, 0);
  LW(wb, 32);
  short8 aA0 = AF(hi * 8), aA1 = AF(16 + hi * 8);
  floatx16 acc = {};

  for (int t = 0; t < nt; t += 2) {
    int k0 = t << 5;
    // ---- tile t (regs wa -> LDS L0)
    STW(L0, wa);
    { int kn = (k0 + 64) < kWmax ? (k0 + 64) : kWmax; LW(wa, kn); }
    short8 aB0 = AF(k0 + 32 + hi * 8), aB1 = AF(k0 + 48 + hi * 8);
    short8 bf0, bf1;
    BRD(L0, 0, bf0); BRD(L0, 1, bf1);
    acc = __builtin_amdgcn_mfma_f32_32x32x16_bf16(aA0, bf0, acc, 0, 0, 0);
    acc = __builtin_amdgcn_mfma_f32_32x32x16_bf16(aA1, bf1, acc, 0, 0, 0);
    // ---- tile t+1 (regs wb -> LDS L1)
    STW(L1, wb);
    { int kn = (k0 + 96) < kWmax ? (k0 + 96) : kWmax; LW(wb, kn); }
    short8 aC0 = AF(k0 + 64 + hi * 8), aC1 = AF(k0 + 80 + hi * 8);
    BRD(L1, 0, bf0); BRD(L1, 1, bf1);
    acc = __builtin_amdgcn_mfma_f32_32x32x16_bf16(aB0, bf0, acc, 0, 0, 0);
    acc = __builtin_amdgcn_mfma_f32_32x32x16_bf16(aB1, bf1, acc, 0, 0, 0);
    aA0 = aC0; aA1 = aC1;
  }
#undef LW
#undef AF
#undef STW
#undef BRD

  // C/D: col = lane&31, row = (reg&3)+8*(reg>>2)+4*(lane>>5)
  unsigned short* outp = reps + (size_t)(l * 32) * N_EMBD + cw + lo;
#pragma unroll
  for (int r = 0; r < 16; ++r) {
    int row = (r & 3) + 8 * (r >> 2) + 4 * hi;
    outp[(size_t)row * N_EMBD] = f2bf(acc[r]);
  }
}

// ---------------- layernorm rows of reps -> rlnswz in blocked layout
// rlnswz elem addr = l*32768 + (d>>3)*256 + b*8 + (d&7). grid 768 x 256, wave/row.
__global__ __launch_bounds__(256) void ln_kernel(
    const unsigned short* __restrict__ reps, const float* __restrict__ gamma,
    const float* __restrict__ beta, unsigned short* __restrict__ rlnswz) {
  int row  = blockIdx.x * 4 + (threadIdx.x >> 6);
  int lane = threadIdx.x & 63;
  int l = row >> 5, b = row & 31;
  const unsigned short* rp = reps + (size_t)row * N_EMBD;

  float x[16];
#pragma unroll
  for (int j = 0; j < 2; ++j) {
    int g = j * 64 + lane;
    ushort8 v = *(const ushort8*)(rp + g * 8);
#pragma unroll
    for (int t = 0; t < 8; ++t) x[j * 8 + t] = bf2f(v[t]);
  }
  float s = 0.f, s2 = 0.f;
#pragma unroll
  for (int i = 0; i < 16; ++i) { s += x[i]; s2 += x[i] * x[i]; }
#pragma unroll
  for (int m = 1; m < 64; m <<= 1) {
    s  += __shfl_xor(s,  m, 64);
    s2 += __shfl_xor(s2, m, 64);
  }
  float mu  = s * (1.f / 1024.f);
  float var = s2 * (1.f / 1024.f) - mu * mu;
  float rs  = rsqrtf(var + 1e-5f);

  unsigned short* op = rlnswz + (size_t)l * 32768 + b * 8;
#pragma unroll
  for (int j = 0; j < 2; ++j) {
    int g = j * 64 + lane;
    float4v g0 = *(const float4v*)(gamma + g * 8);
    float4v g1 = *(const float4v*)(gamma + g * 8 + 4);
    float4v b0 = *(const float4v*)(beta + g * 8);
    float4v b1 = *(const float4v*)(beta + g * 8 + 4);
    ushort8 o;
#pragma unroll
    for (int t = 0; t < 4; ++t) {
      o[t]     = f2bf((x[j * 8 + t]     - mu) * rs * g0[t] + b0[t]);
      o[t + 4] = f2bf((x[j * 8 + 4 + t] - mu) * rs * g1[t] + b1[t]);
    }
    *(ushort8*)(op + (size_t)g * 256) = o;
  }
}

// ---------------- decoder: barrier-free, wave-private reg-staged GEMM
// flat grid: exactly 864 active tiles (no early-exit blocks), K = 1024 for all.
__global__ __launch_bounds__(256) void dec_kernel(
    const unsigned short* __restrict__ rlnswz, const float* __restrict__ Wd,
    float* __restrict__ out) {
  __shared__ float ldsW[4][2][32 * 36];
  int id = blockIdx.x;
  int l, ti;
  if (id < 384)      { l = 48 + (id >> 4); ti = id & 15; }
  else if (id < 768) { int j = id - 384; l = j >> 3; ti = j & 7; }
  else               { int j = id - 768; l = 72 + (j >> 2); ti = j & 3; }
  int S, off; chunk_info(l, S, off);

  int tid = threadIdx.x, w = tid >> 6, lane = tid & 63;
  int lo = lane & 31, hi = lane >> 5;
  int r8 = lane >> 3, c4 = (lane & 7) << 2;
  int cw = ti * 128 + w * 32;

  const float* gW = Wd + (size_t)l * (N_EMBD * 2048) + (size_t)r8 * 2048 + cw + c4;
  const unsigned short* Ab = rlnswz + (size_t)l * 32768 + lo * 8;
  float* L0 = &ldsW[w][0][0];
  float* L1 = &ldsW[w][1][0];
  const int nt = N_EMBD >> 5;         // 32
  const int kAmax = N_EMBD - 8;
  const int kWmax = (nt - 1) << 5;    // 992

#define LW(dst, k0) { int kk_ = (k0); _Pragma("unroll") \
    for (int q = 0; q < 4; ++q) dst[q] = *(const float4v*)(gW + (size_t)(kk_ + 8 * q) * 2048); }
#define AF(ka) (*(const short8*)(Ab + (size_t)((ka) < kAmax ? (ka) : kAmax) * 32))
#define STW(L, src) { _Pragma("unroll") \
    for (int q = 0; q < 4; ++q) *(float4v*)((L) + (r8 + 8 * q) * 36 + c4) = src[q]; }
#define BRD(L, ks, dst) { _Pragma("unroll") \
    for (int j = 0; j < 8; ++j) dst[j] = (short)f2bf((L)[((ks) * 16 + hi * 8 + j) * 36 + lo]); }

  float4v wa[4], wb[4];
  LW(wa, 0);
  LW(wb, 32);
  short8 aA0 = AF(hi * 8), aA1 = AF(16 + hi * 8);
  floatx16 acc = {};

  for (int t = 0; t < nt; t += 2) {
    int k0 = t << 5;
    STW(L0, wa);
    { int kn = (k0 + 64) < kWmax ? (k0 + 64) : kWmax; LW(wa, kn); }
    short8 aB0 = AF(k0 + 32 + hi * 8), aB1 = AF(k0 + 48 + hi * 8);
    short8 bf0, bf1;
    BRD(L0, 0, bf0); BRD(L0, 1, bf1);
    acc = __builtin_amdgcn_mfma_f32_32x32x16_bf16(aA0, bf0, acc, 0, 0, 0);
    acc = __builtin_amdgcn_mfma_f32_32x32x16_bf16(aA1, bf1, acc, 0, 0, 0);
    STW(L1, wb);
    { int kn = (k0 + 96) < kWmax ? (k0 + 96) : kWmax; LW(wb, kn); }
    short8 aC0 = AF(k0 + 64 + hi * 8), aC1 = AF(k0 + 80 + hi * 8);
    BRD(L1, 0, bf0); BRD(L1, 1, bf1);
    acc = __builtin_amdgcn_mfma_f32_32x32x16_bf16(aB0, bf0, acc, 0, 0, 0);
    acc = __builtin_amdgcn_mfma_f32_32x32x16_bf16(aB1, bf1, acc, 0, 0, 0);
    aA0 = aC0; aA1 = aC1;
  }
#undef LW
#undef AF
#undef STW
#undef BRD

#pragma unroll
  for (int r = 0; r < 16; ++r) {
    int row = (r & 3) + 8 * (r >> 2) + 4 * hi;  // batch index
    out[(size_t)row * NW + off + cw + lo] = acc[r];
  }
}

extern "C" void kernel_launch(void* const* d_in, const int* in_sizes, int n_in,
                              void* d_out, int out_size, void* d_ws, size_t ws_size,
                              hipStream_t stream) {
  const float* P  = (const float*)d_in[0];
  const float* We = (const float*)d_in[1];
  const float* Wd = (const float*)d_in[2];
  const float* g  = (const float*)d_in[3];
  const float* bt = (const float*)d_in[4];
  float* out = (float*)d_out;

  unsigned short* xswz   = (unsigned short*)d_ws;                    // NW*32 bf16 = 7.08 MB
  unsigned short* reps   = xswz + (size_t)NW * 32;                   // 6.29 MB
  unsigned short* rlnswz = reps + (size_t)NCHUNK * 32 * N_EMBD;      // 6.29 MB

  xpose_kernel<<<(NW / 8) * 32 / 256, 256, 0, stream>>>(P, xswz);
  enc_kernel<<<768, 256, 0, stream>>>(xswz, We, reps);
  ln_kernel<<<768, 256, 0, stream>>>(reps, g, bt, rlnswz);
  dec_kernel<<<864, 256, 0, stream>>>(rlnswz, Wd, out);
}

// Round 4
// 207.617 us; speedup vs baseline: 1.0366x; 1.0366x over previous
//
#include <hip/hip_runtime.h>
#include <hip/hip_bf16.h>

#define N_EMBD 1024
#define NW     110592
#define NCHUNK 96

typedef __attribute__((ext_vector_type(8)))  short          short8;
typedef __attribute__((ext_vector_type(8)))  unsigned short ushort8;
typedef __attribute__((ext_vector_type(16))) float          floatx16;
typedef __attribute__((ext_vector_type(4)))  float          float4v;

// chunk sizes: 48 x 1024, 24 x 2048, 24 x 512
__device__ __forceinline__ void chunk_info(int l, int& S, int& off) {
  if (l < 48)      { S = 1024; off = l * 1024; }
  else if (l < 72) { S = 2048; off = 49152 + (l - 48) * 2048; }
  else             { S = 512;  off = 98304 + (l - 72) * 512; }
}

// fp32 -> bf16 round-to-nearest-even
__device__ __forceinline__ unsigned short f2bf(float f) {
  unsigned u = __float_as_uint(f);
  u += 0x7fffu + ((u >> 16) & 1u);
  return (unsigned short)(u >> 16);
}
__device__ __forceinline__ float bf2f(unsigned short u) {
  return __uint_as_float(((unsigned)u) << 16);
}

#define GLOAD_LDS16(g, l) \
  __builtin_amdgcn_global_load_lds((const __attribute__((address_space(1))) unsigned int*)(g), \
                                   (__attribute__((address_space(3))) unsigned int*)(l), 16, 0, 0)

// ---------------- transpose: xswz[kb][b][e] = bf16(P[b][kb*8+e])
__global__ __launch_bounds__(256) void xpose_kernel(
    const float* __restrict__ P, unsigned short* __restrict__ xswz) {
  int t = blockIdx.x * 256 + threadIdx.x;   // t < (NW/8)*32
  int b = t & 31, kb = t >> 5;
  const float* src = P + (size_t)b * NW + (size_t)kb * 8;
  float4v v0 = *(const float4v*)(src);
  float4v v1 = *(const float4v*)(src + 4);
  ushort8 o;
#pragma unroll
  for (int j = 0; j < 4; ++j) { o[j] = f2bf(v0[j]); o[j + 4] = f2bf(v1[j]); }
  *(ushort8*)(xswz + (size_t)t * 8) = o;
}

// ---------------- encoder: reps[l*32+b][d] = sum_k x[b,off+k] * We[l][k][d]
// 384 blocks x 512 thr (8 waves). 32(batch) x 256(col) tile, K-step 32, LDS dbuf,
// per-XCD LPT: XCD x = id&7 owns chunks {x+8m}, heavy-first, same-chunk tiles contiguous.
__global__ __launch_bounds__(512) void enc_kernel(
    const unsigned short* __restrict__ xswz, const float* __restrict__ We,
    unsigned short* __restrict__ reps) {
  __shared__ float Bt[2][32][256];
  int id = blockIdx.x;
  int x = id & 7, j = id >> 3;                 // j in 0..47 per XCD
  int l, ti;
  if (j < 12)      { l = 48 + x + 8 * (j >> 2); ti = j & 3; }        // heavy  S=2048
  else if (j < 36) { int jm = j - 12; l = x + 8 * (jm >> 2); ti = jm & 3; }  // medium S=1024
  else             { int jl = j - 36; l = 72 + x + 8 * (jl >> 2); ti = jl & 3; } // light S=512
  int S, off; chunk_info(l, S, off);

  int tid = threadIdx.x, w = tid >> 6, lane = tid & 63;
  int lo = lane & 31, hi = lane >> 5;
  int c0 = ti * 256;

  const float* Wb = We + (size_t)l * (2048 * N_EMBD) + c0 + (lane << 2);
  const unsigned short* Ab = xswz + (size_t)off * 32 + lo * 8;

#define STAGE(buf, k0) { _Pragma("unroll") \
    for (int q = 0; q < 4; ++q) \
      GLOAD_LDS16(Wb + (size_t)((k0) + w * 4 + q) * N_EMBD, &Bt[buf][w * 4 + q][0]); }

  floatx16 acc = {};
  STAGE(0, 0);
  __syncthreads();

  for (int k0 = 0; k0 < S; k0 += 32) {
    int cur = (k0 >> 5) & 1;
    if (k0 + 32 < S) STAGE(cur ^ 1, k0 + 32);
#pragma unroll
    for (int ks = 0; ks < 2; ++ks) {
      int ka = k0 + ks * 16 + hi * 8;
      short8 af = *(const short8*)(Ab + (size_t)ka * 32);
      short8 bf;
#pragma unroll
      for (int jj = 0; jj < 8; ++jj)
        bf[jj] = (short)f2bf(Bt[cur][ks * 16 + hi * 8 + jj][w * 32 + lo]);
      acc = __builtin_amdgcn_mfma_f32_32x32x16_bf16(af, bf, acc, 0, 0, 0);
    }
    __syncthreads();
  }
#undef STAGE

  // C/D: col = lane&31, row = (reg&3)+8*(reg>>2)+4*(lane>>5)
  unsigned short* outp = reps + (size_t)(l * 32) * N_EMBD + c0 + w * 32 + lo;
#pragma unroll
  for (int r = 0; r < 16; ++r) {
    int row = (r & 3) + 8 * (r >> 2) + 4 * hi;
    outp[(size_t)row * N_EMBD] = f2bf(acc[r]);
  }
}

// ---------------- layernorm rows of reps -> rlnswz in blocked layout
// rlnswz elem addr = l*32768 + (d>>3)*256 + b*8 + (d&7). grid 768 x 256, wave/row.
__global__ __launch_bounds__(256) void ln_kernel(
    const unsigned short* __restrict__ reps, const float* __restrict__ gamma,
    const float* __restrict__ beta, unsigned short* __restrict__ rlnswz) {
  int row  = blockIdx.x * 4 + (threadIdx.x >> 6);
  int lane = threadIdx.x & 63;
  int l = row >> 5, b = row & 31;
  const unsigned short* rp = reps + (size_t)row * N_EMBD;

  float x[16];
#pragma unroll
  for (int j = 0; j < 2; ++j) {
    int g = j * 64 + lane;
    ushort8 v = *(const ushort8*)(rp + g * 8);
#pragma unroll
    for (int t = 0; t < 8; ++t) x[j * 8 + t] = bf2f(v[t]);
  }
  float s = 0.f, s2 = 0.f;
#pragma unroll
  for (int i = 0; i < 16; ++i) { s += x[i]; s2 += x[i] * x[i]; }
#pragma unroll
  for (int m = 1; m < 64; m <<= 1) {
    s  += __shfl_xor(s,  m, 64);
    s2 += __shfl_xor(s2, m, 64);
  }
  float mu  = s * (1.f / 1024.f);
  float var = s2 * (1.f / 1024.f) - mu * mu;
  float rs  = rsqrtf(var + 1e-5f);

  unsigned short* op = rlnswz + (size_t)l * 32768 + b * 8;
#pragma unroll
  for (int j = 0; j < 2; ++j) {
    int g = j * 64 + lane;
    float4v g0 = *(const float4v*)(gamma + g * 8);
    float4v g1 = *(const float4v*)(gamma + g * 8 + 4);
    float4v b0 = *(const float4v*)(beta + g * 8);
    float4v b1 = *(const float4v*)(beta + g * 8 + 4);
    ushort8 o;
#pragma unroll
    for (int t = 0; t < 4; ++t) {
      o[t]     = f2bf((x[j * 8 + t]     - mu) * rs * g0[t] + b0[t]);
      o[t + 4] = f2bf((x[j * 8 + 4 + t] - mu) * rs * g1[t] + b1[t]);
    }
    *(ushort8*)(op + (size_t)g * 256) = o;
  }
}

// ---------------- decoder: out[b][off+j] = sum_d rln[l*32+b][d] * Wd[l][d][j]
// 432 blocks x 512 thr, 32 x 256 tiles, K = 1024. Per-XCD LPT (8/4/2 tiles per chunk).
__global__ __launch_bounds__(512) void dec_kernel(
    const unsigned short* __restrict__ rlnswz, const float* __restrict__ Wd,
    float* __restrict__ out) {
  __shared__ float Bt[2][32][256];
  int id = blockIdx.x;
  int x = id & 7, j = id >> 3;                 // j in 0..53 per XCD
  int l, ti;
  if (j < 24)      { l = 48 + x + 8 * (j >> 3); ti = j & 7; }        // heavy  S=2048
  else if (j < 48) { int jm = j - 24; l = x + 8 * (jm >> 2); ti = jm & 3; }  // medium S=1024
  else             { int jl = j - 48; l = 72 + x + 8 * (jl >> 1); ti = jl & 1; } // light S=512
  int S, off; chunk_info(l, S, off);

  int tid = threadIdx.x, w = tid >> 6, lane = tid & 63;
  int lo = lane & 31, hi = lane >> 5;
  int c0 = ti * 256;

  const float* Wb = Wd + (size_t)l * (N_EMBD * 2048) + c0 + (lane << 2);
  const unsigned short* Ab = rlnswz + (size_t)l * 32768 + lo * 8;

#define STAGE(buf, k0) { _Pragma("unroll") \
    for (int q = 0; q < 4; ++q) \
      GLOAD_LDS16(Wb + (size_t)((k0) + w * 4 + q) * 2048, &Bt[buf][w * 4 + q][0]); }

  floatx16 acc = {};
  STAGE(0, 0);
  __syncthreads();

  for (int k0 = 0; k0 < N_EMBD; k0 += 32) {
    int cur = (k0 >> 5) & 1;
    if (k0 + 32 < N_EMBD) STAGE(cur ^ 1, k0 + 32);
#pragma unroll
    for (int ks = 0; ks < 2; ++ks) {
      int ka = k0 + ks * 16 + hi * 8;
      short8 af = *(const short8*)(Ab + (size_t)ka * 32);
      short8 bf;
#pragma unroll
      for (int jj = 0; jj < 8; ++jj)
        bf[jj] = (short)f2bf(Bt[cur][ks * 16 + hi * 8 + jj][w * 32 + lo]);
      acc = __builtin_amdgcn_mfma_f32_32x32x16_bf16(af, bf, acc, 0, 0, 0);
    }
    __syncthreads();
  }
#undef STAGE

#pragma unroll
  for (int r = 0; r < 16; ++r) {
    int row = (r & 3) + 8 * (r >> 2) + 4 * hi;  // batch index
    out[(size_t)row * NW + off + c0 + w * 32 + lo] = acc[r];
  }
}

extern "C" void kernel_launch(void* const* d_in, const int* in_sizes, int n_in,
                              void* d_out, int out_size, void* d_ws, size_t ws_size,
                              hipStream_t stream) {
  const float* P  = (const float*)d_in[0];
  const float* We = (const float*)d_in[1];
  const float* Wd = (const float*)d_in[2];
  const float* g  = (const float*)d_in[3];
  const float* bt = (const float*)d_in[4];
  float* out = (float*)d_out;

  unsigned short* xswz   = (unsigned short*)d_ws;                    // NW*32 bf16 = 7.08 MB
  unsigned short* reps   = xswz + (size_t)NW * 32;                   // 6.29 MB
  unsigned short* rlnswz = reps + (size_t)NCHUNK * 32 * N_EMBD;      // 6.29 MB

  xpose_kernel<<<(NW / 8) * 32 / 256, 256, 0, stream>>>(P, xswz);
  enc_kernel<<<384, 512, 0, stream>>>(xswz, We, reps);
  ln_kernel<<<768, 256, 0, stream>>>(reps, g, bt, rlnswz);
  dec_kernel<<<432, 512, 0, stream>>>(rlnswz, Wd, out);
}